// Round 2
// baseline (662.389 us; speedup 1.0000x reference)
//
#include <hip/hip_runtime.h>

#define B_N 4
#define S_LEN 4096
#define D_DIM 256

typedef __attribute__((ext_vector_type(8))) short short8;
typedef __attribute__((ext_vector_type(4))) short short4_;
typedef __attribute__((ext_vector_type(4))) float f32x4;
typedef __attribute__((ext_vector_type(4))) int int4_;

static __device__ __forceinline__ unsigned short f2bf(float f) {
  unsigned u = __builtin_bit_cast(unsigned, f);
  u += 0x7fffu + ((u >> 16) & 1u);
  return (unsigned short)(u >> 16);
}

#if __has_builtin(__builtin_amdgcn_mfma_f32_16x16x16bf16_1k)
#define MFMA16(a, b, c) __builtin_amdgcn_mfma_f32_16x16x16bf16_1k((a), (b), (c), 0, 0, 0)
#else
static __device__ __forceinline__ f32x4 mfma16_asm(short4_ a, short4_ b, f32x4 c) {
  asm volatile("v_mfma_f32_16x16x16_bf16 %0, %1, %2, %0" : "+v"(c) : "v"(a), "v"(b));
  return c;
}
#define MFMA16(a, b, c) mfma16_asm((a), (b), (c))
#endif

// ---------------- Projection: Out[m][n] = sum_k X[m][k] * W[n][k]  (bf16 out) ----------------
__global__ __launch_bounds__(256, 2)
void proj_kernel(const float* __restrict__ X0, const float* __restrict__ X1,
                 const float* __restrict__ X2,
                 const float* __restrict__ W0, const float* __restrict__ W1,
                 const float* __restrict__ W2,
                 unsigned short* __restrict__ O0, unsigned short* __restrict__ O1,
                 unsigned short* __restrict__ O2) {
  __shared__ __align__(16) unsigned char sA[16384];  // 128 rows x 64 bf16 (128B/row), swizzled
  __shared__ __align__(16) unsigned char sB[16384];

  const int z = (int)blockIdx.z;
  const float* X = (z == 0) ? X0 : (z == 1) ? X1 : X2;
  const float* W = (z == 0) ? W0 : (z == 1) ? W1 : W2;
  unsigned short* O = (z == 0) ? O0 : (z == 1) ? O1 : O2;
  const float mult = (z == 0) ? 0.0625f : 1.0f;  // fold 1/sqrt(D) into Q

  const int t = (int)threadIdx.x;
  const int l = t & 63, w = t >> 6;
  const int lm = l & 15, g = l >> 4;
  const int wr = w >> 1, wc = w & 1;
  const int mb = (int)blockIdx.x * 128;
  const int nb = (int)blockIdx.y * 128;

  f32x4 acc[4][4];
#pragma unroll
  for (int i = 0; i < 4; ++i)
#pragma unroll
    for (int j = 0; j < 4; ++j) acc[i][j] = (f32x4){0.f, 0.f, 0.f, 0.f};

  for (int ks = 0; ks < 4; ++ks) {
    const int k0 = ks * 64;
#pragma unroll
    for (int i = 0; i < 4; ++i) {
      const int c = t + i * 256;
      const int row = c >> 3;
      const int kc = (c & 7) * 8;
      const float* xp = X + (size_t)(mb + row) * D_DIM + k0 + kc;
      const float* wp = W + (size_t)(nb + row) * D_DIM + k0 + kc;
      f32x4 x0 = *(const f32x4*)xp;
      f32x4 x1 = *(const f32x4*)(xp + 4);
      f32x4 w0 = *(const f32x4*)wp;
      f32x4 w1 = *(const f32x4*)(wp + 4);
      short8 xa, wa;
#pragma unroll
      for (int j = 0; j < 4; ++j) {
        xa[j] = (short)f2bf(x0[j]);
        xa[j + 4] = (short)f2bf(x1[j]);
        wa[j] = (short)f2bf(w0[j]);
        wa[j + 4] = (short)f2bf(w1[j]);
      }
      const int off = row * 128 + ((kc * 2) ^ ((row & 7) << 4));
      *(short8*)&sA[off] = xa;
      *(short8*)&sB[off] = wa;
    }
    __syncthreads();
#pragma unroll
    for (int kk = 0; kk < 2; ++kk) {
      short8 af[4], bg[4];
#pragma unroll
      for (int mi = 0; mi < 4; ++mi) {
        const int row = wr * 64 + mi * 16 + lm;
        af[mi] = *(const short8*)&sA[row * 128 + (((kk * 32 + g * 8) * 2) ^ ((row & 7) << 4))];
      }
#pragma unroll
      for (int ni = 0; ni < 4; ++ni) {
        const int row = wc * 64 + ni * 16 + lm;
        bg[ni] = *(const short8*)&sB[row * 128 + (((kk * 32 + g * 8) * 2) ^ ((row & 7) << 4))];
      }
#pragma unroll
      for (int mi = 0; mi < 4; ++mi)
#pragma unroll
        for (int ni = 0; ni < 4; ++ni)
          acc[mi][ni] = __builtin_amdgcn_mfma_f32_16x16x32_bf16(af[mi], bg[ni], acc[mi][ni], 0, 0, 0);
    }
    __syncthreads();
  }

#pragma unroll
  for (int mi = 0; mi < 4; ++mi)
#pragma unroll
    for (int ni = 0; ni < 4; ++ni)
#pragma unroll
      for (int r = 0; r < 4; ++r) {
        const int mg = mb + wr * 64 + mi * 16 + g * 4 + r;
        const int ng = nb + wc * 64 + ni * 16 + lm;
        O[(size_t)mg * D_DIM + ng] = f2bf(acc[mi][ni][r] * mult);
      }
}

// ---------------- Flash attention, causal + key-padding mask ----------------
__global__ __launch_bounds__(256, 2)
void attn_kernel(const unsigned short* __restrict__ Qb,
                 const unsigned short* __restrict__ Kb,
                 const unsigned short* __restrict__ Vb,
                 const int* __restrict__ amask,
                 float* __restrict__ Out) {
  __shared__ __align__(16) unsigned char sK[32768];   // 64 keys x 256 bf16, row-swizzled (16B granule)
  __shared__ __align__(16) unsigned char sVT[32768];  // V^T: 256 d-rows x 64 keys bf16, swizzled (8B granule)

  const int t = (int)threadIdx.x;
  const int l = t & 63;
  const int w = t >> 6;
  const int lm = l & 15;
  const int g = l >> 4;
  const int b = (int)blockIdx.x >> 6;
  const int qb = (int)blockIdx.x & 63;
  const size_t bS = (size_t)b * S_LEN;

  // Q fragments (B-operand of swapped QK^T): n = q = lm, k-chunk = ch*32 + g*8 + j
  short8 qf[8];
  {
    const unsigned short* qp = Qb + (bS + (size_t)(qb * 64 + w * 16 + lm)) * D_DIM + g * 8;
#pragma unroll
    for (int ch = 0; ch < 8; ++ch) qf[ch] = *(const short8*)(qp + ch * 32);
  }

  f32x4 o[16];
#pragma unroll
  for (int dt = 0; dt < 16; ++dt) o[dt] = (f32x4){0.f, 0.f, 0.f, 0.f};
  float mrun = -1e30f, lrun = 0.f;
  const int q_g = qb * 64 + w * 16 + lm;

  for (int tt = 0; tt <= qb; ++tt) {
    const int k0 = tt * 64;
    // ---- stage K (row-major swizzled) and V^T (scalar-transpose, swizzled) ----
#pragma unroll
    for (int i = 0; i < 8; ++i) {
      const int c = t + i * 256;
      const int row = c >> 5;        // key within tile
      const int d8 = (c & 31) << 3;  // d chunk start
      {
        int4_ kvv = *(const int4_*)(Kb + (bS + (size_t)(k0 + row)) * D_DIM + d8);
        *(int4_*)&sK[row * 512 + ((d8 * 2) ^ ((row & 7) << 4))] = kvv;
      }
      {
        int4_ vvv = *(const int4_*)(Vb + (bS + (size_t)(k0 + row)) * D_DIM + d8);
        const unsigned short* pv = (const unsigned short*)&vvv;
#pragma unroll
        for (int jj = 0; jj < 8; ++jj) {
          const int d = d8 + jj;
          const int swz = (((d >> 4) ^ d) & 15) << 3;
          *(unsigned short*)&sVT[d * 128 + ((row * 2) ^ swz)] = pv[jj];
        }
      }
    }
    __syncthreads();

    // ---- QK^T (S^T = K * Q^T): C col = q (lm), C row = key-in-16 (g*4+r), 4 key subtiles s ----
    f32x4 sacc[4];
#pragma unroll
    for (int s = 0; s < 4; ++s) sacc[s] = (f32x4){0.f, 0.f, 0.f, 0.f};
#pragma unroll
    for (int ch = 0; ch < 8; ++ch) {
#pragma unroll
      for (int s = 0; s < 4; ++s) {
        const int key = s * 16 + lm;
        const int off = key * 512 + (((ch * 32 + g * 8) * 2) ^ ((key & 7) << 4));
        short8 kf = *(const short8*)&sK[off];
        sacc[s] = __builtin_amdgcn_mfma_f32_16x16x32_bf16(kf, qf[ch], sacc[s], 0, 0, 0);
      }
    }

    // ---- online softmax (stats per q = lm, replicated across the 4 lane groups) ----
    float sv[4][4];
    float tmax = -1e30f;
#pragma unroll
    for (int s = 0; s < 4; ++s) {
      const int4_ mw = *(const int4_*)(amask + bS + k0 + s * 16 + g * 4);
#pragma unroll
      for (int r = 0; r < 4; ++r) {
        const int key_g = k0 + s * 16 + g * 4 + r;
        const bool ok = (key_g <= q_g) && (mw[r] != 0);
        const float x = ok ? sacc[s][r] : -1e30f;
        sv[s][r] = x;
        tmax = fmaxf(tmax, x);
      }
    }
    tmax = fmaxf(tmax, __shfl_xor(tmax, 16));
    tmax = fmaxf(tmax, __shfl_xor(tmax, 32));
    const float mnew = fmaxf(mrun, tmax);
    const float corr = __builtin_amdgcn_exp2f((mrun - mnew) * 1.44269504f);
    mrun = mnew;

    float psum = 0.f;
    short4_ pk[4];
#pragma unroll
    for (int s = 0; s < 4; ++s) {
#pragma unroll
      for (int r = 0; r < 4; ++r) {
        const float p = __builtin_amdgcn_exp2f((sv[s][r] - mnew) * 1.44269504f);
        psum += p;
        pk[s][r] = (short)f2bf(p);
      }
    }
    psum += __shfl_xor(psum, 16);
    psum += __shfl_xor(psum, 32);
    lrun = lrun * corr + psum;

    // rescale O (O rows are q = g*4+r -> fetch corr from lane g*4+r; stats replicated per lm)
    float cr[4];
#pragma unroll
    for (int r = 0; r < 4; ++r) cr[r] = __shfl(corr, g * 4 + r);
#pragma unroll
    for (int dt = 0; dt < 16; ++dt)
#pragma unroll
      for (int r = 0; r < 4; ++r) o[dt][r] *= cr[r];

    // ---- PV: A = P (in-lane), B = V^T via plain 8B LDS reads (compiler-managed waits) ----
#pragma unroll
    for (int dt = 0; dt < 16; ++dt) {
      const int d = dt * 16 + lm;
      const int swz = (((d >> 4) ^ d) & 15) << 3;  // = ((dt ^ lm) & 15) << 3
#pragma unroll
      for (int s = 0; s < 4; ++s) {
        short4_ vf = *(const short4_*)&sVT[d * 128 + ((s * 32 + g * 8) ^ swz)];
        o[dt] = MFMA16(pk[s], vf, o[dt]);
      }
    }
    __syncthreads();
  }

  // ---- epilogue: divide by l, write fp32 ----
  const float inv = 1.f / lrun;
  float ir[4];
#pragma unroll
  for (int r = 0; r < 4; ++r) ir[r] = __shfl(inv, g * 4 + r);
  float* op = Out + (bS + (size_t)(qb * 64 + w * 16)) * D_DIM;
#pragma unroll
  for (int dt = 0; dt < 16; ++dt)
#pragma unroll
    for (int r = 0; r < 4; ++r)
      op[(size_t)(g * 4 + r) * D_DIM + dt * 16 + lm] = o[dt][r] * ir[r];
}

extern "C" void kernel_launch(void* const* d_in, const int* in_sizes, int n_in,
                              void* d_out, int out_size, void* d_ws, size_t ws_size,
                              hipStream_t stream) {
  const float* x_q = (const float*)d_in[0];
  const float* x_k = (const float*)d_in[1];
  const float* x_v = (const float*)d_in[2];
  const int* amask = (const int*)d_in[3];
  const float* Wq = (const float*)d_in[4];
  const float* Wk = (const float*)d_in[5];
  const float* Wv = (const float*)d_in[6];

  unsigned short* Qb = (unsigned short*)d_ws;
  unsigned short* Kb = Qb + (size_t)B_N * S_LEN * D_DIM;
  unsigned short* Vb = Kb + (size_t)B_N * S_LEN * D_DIM;

  dim3 pg(128, 2, 3);
  proj_kernel<<<pg, dim3(256), 0, stream>>>(x_q, x_k, x_v, Wq, Wk, Wv, Qb, Kb, Vb);
  attn_kernel<<<dim3(B_N * (S_LEN / 64)), dim3(256), 0, stream>>>(Qb, Kb, Vb, amask, (float*)d_out);
}